// Round 21
// baseline (247.365 us; speedup 1.0000x reference)
//
#include <hip/hip_runtime.h>
#include <hip/hip_bf16.h>
#include <math.h>

#define BB 128
#define NN2 1024
#define NN3 256
#define NN4 64
#define DD 128
#define MLPD 512
#define EPSF 1e-5f

typedef short bf16x8 __attribute__((ext_vector_type(8)));
typedef float f32x4 __attribute__((ext_vector_type(4)));

__device__ inline ushort f2b(float x) {
    __hip_bfloat16 h = __float2bfloat16(x);
    return __builtin_bit_cast(ushort, h);
}
__device__ inline float b2f(ushort u) {
    unsigned int v = ((unsigned int)u) << 16;
    return __builtin_bit_cast(float, v);
}
// tanh-form GELU via exp
__device__ inline float gelu_f(float u) {
    float t = 0.7978845608f * u + 0.0356774081f * (u * u * u);
    float e = __expf(2.f * t);
    return u - u * __builtin_amdgcn_rcpf(e + 1.f);
}

#define MFMA(a, b, c) __builtin_amdgcn_mfma_f32_16x16x32_bf16((a), (b), (c), 0, 0, 0)

// XOR-swizzled LDS tile addressing: byte ^= (row*16) & (stride-16).
__device__ inline char* swad(char* base, int row, int bytecol, int strideB) {
    return base + (size_t)row * strideB + ((bytecol) ^ ((row << 4) & (strideB - 16)));
}

// LN of rows (8 threads/row) from global -> bf16 LDS tile [rows][STRIDE]
template <int STRIDE>
__device__ inline void ln_stage(const float* __restrict__ x, long base,
                                const float* __restrict__ w, const float* __restrict__ b,
                                ushort xn[][STRIDE], int t)
{
    int r = t >> 3, l8 = t & 7;
    const float4* xr4 = reinterpret_cast<const float4*>(x + (base + r) * DD);
    float4 v[4];
#pragma unroll
    for (int j = 0; j < 4; ++j) v[j] = xr4[l8 * 4 + j];
    float s = 0.f;
#pragma unroll
    for (int j = 0; j < 4; ++j) s += v[j].x + v[j].y + v[j].z + v[j].w;
#pragma unroll
    for (int m = 1; m <= 4; m <<= 1) s += __shfl_xor(s, m, 64);
    float mean = s * (1.f / 128.f);
    float s2 = 0.f;
#pragma unroll
    for (int j = 0; j < 4; ++j) {
        v[j].x -= mean; v[j].y -= mean; v[j].z -= mean; v[j].w -= mean;
        s2 += v[j].x * v[j].x + v[j].y * v[j].y + v[j].z * v[j].z + v[j].w * v[j].w;
    }
#pragma unroll
    for (int m = 1; m <= 4; m <<= 1) s2 += __shfl_xor(s2, m, 64);
    float rstd = rsqrtf(s2 * (1.f / 128.f) + EPSF);
    int c0 = l8 * 16;
#pragma unroll
    for (int j = 0; j < 4; ++j) {
        int c = c0 + j * 4;
        float o0 = v[j].x * rstd * w[c] + b[c];
        float o1 = v[j].y * rstd * w[c + 1] + b[c + 1];
        float o2 = v[j].z * rstd * w[c + 2] + b[c + 2];
        float o3 = v[j].w * rstd * w[c + 3] + b[c + 3];
        uint2 uu;
        uu.x = (unsigned int)f2b(o0) | ((unsigned int)f2b(o1) << 16);
        uu.y = (unsigned int)f2b(o2) | ((unsigned int)f2b(o3) << 16);
        *reinterpret_cast<uint2*>(&xn[r][c]) = uu;
    }
}

// LN (8 threads/row) from global -> swizzled bf16 LDS tile (256B stride)
__device__ inline void ln_stage_s(const float* __restrict__ x, long base,
                                  const float* __restrict__ w, const float* __restrict__ b,
                                  char* R, int t)
{
    int r = t >> 3, l8 = t & 7;
    const float4* xr4 = reinterpret_cast<const float4*>(x + (base + r) * DD);
    float4 v[4];
#pragma unroll
    for (int j = 0; j < 4; ++j) v[j] = xr4[l8 * 4 + j];
    float s = 0.f;
#pragma unroll
    for (int j = 0; j < 4; ++j) s += v[j].x + v[j].y + v[j].z + v[j].w;
#pragma unroll
    for (int m = 1; m <= 4; m <<= 1) s += __shfl_xor(s, m, 64);
    float mean = s * (1.f / 128.f);
    float s2 = 0.f;
#pragma unroll
    for (int j = 0; j < 4; ++j) {
        v[j].x -= mean; v[j].y -= mean; v[j].z -= mean; v[j].w -= mean;
        s2 += v[j].x * v[j].x + v[j].y * v[j].y + v[j].z * v[j].z + v[j].w * v[j].w;
    }
#pragma unroll
    for (int m = 1; m <= 4; m <<= 1) s2 += __shfl_xor(s2, m, 64);
    float rstd = rsqrtf(s2 * (1.f / 128.f) + EPSF);
    int c0 = l8 * 16;
#pragma unroll
    for (int j = 0; j < 4; ++j) {
        int c = c0 + j * 4;
        float o0 = v[j].x * rstd * w[c] + b[c];
        float o1 = v[j].y * rstd * w[c + 1] + b[c + 1];
        float o2 = v[j].z * rstd * w[c + 2] + b[c + 2];
        float o3 = v[j].w * rstd * w[c + 3] + b[c + 3];
        uint2 uu;
        uu.x = (unsigned int)f2b(o0) | ((unsigned int)f2b(o1) << 16);
        uu.y = (unsigned int)f2b(o2) | ((unsigned int)f2b(o3) << 16);
        *reinterpret_cast<uint2*>(swad(R, r, c * 2, 256)) = uu;
    }
}

// -------- merged prep: blocks 0-15 weight transpose; 16.. pe@W folds (fp32)
__global__ __launch_bounds__(256) void prep_all(
    const float* __restrict__ q1w, const float* __restrict__ q2w,
    const float* __restrict__ k1w, const float* __restrict__ v1w,
    const float* __restrict__ k2w, const float* __restrict__ v2w,
    const float* __restrict__ ff1w, const float* __restrict__ ff2w,
    const float* __restrict__ rpw,
    const float* __restrict__ pe2, const float* __restrict__ pe3, const float* __restrict__ pe4,
    const float* __restrict__ q1b, const float* __restrict__ q2b,
    const float* __restrict__ k1b, const float* __restrict__ v1b,
    const float* __restrict__ k2b, const float* __restrict__ v2b,
    ushort* __restrict__ Wqt, ushort* __restrict__ Wkv3t, ushort* __restrict__ Wkv4t,
    ushort* __restrict__ W1t, ushort* __restrict__ W2t, ushort* __restrict__ RpT,
    float* __restrict__ peq, float* __restrict__ pekv3, float* __restrict__ pekv4)
{
    __shared__ ushort trans[4][64][88];
    if (blockIdx.x < 16) {
        int w = threadIdx.x >> 6, l = threadIdx.x & 63;
        int tile = blockIdx.x * 4 + w;  // 0..63
        const float* src; ushort* dst; int K, N, tk, tn;
        if (tile < 24) {
            int job = tile >> 2, rel = tile & 3;
            K = 128; N = 128; tk = rel >> 1; tn = rel & 1;
            if      (job == 0) { src = q1w; dst = Wqt; }
            else if (job == 1) { src = q2w; dst = Wqt + 16384; }
            else if (job == 2) { src = k1w; dst = Wkv3t; }
            else if (job == 3) { src = v1w; dst = Wkv3t + 16384; }
            else if (job == 4) { src = k2w; dst = Wkv4t; }
            else               { src = v2w; dst = Wkv4t + 16384; }
        } else if (tile < 40) {
            int rel = tile - 24; src = ff1w; dst = W1t; K = 128; N = 512; tk = rel >> 3; tn = rel & 7;
        } else if (tile < 56) {
            int rel = tile - 40; src = ff2w; dst = W2t; K = 512; N = 128; tk = rel >> 1; tn = rel & 1;
        } else {
            int rel = tile - 56; src = rpw; dst = RpT; K = 256; N = 128; tk = rel >> 1; tn = rel & 1;
        }
        int k0 = tk * 64, n0 = tn * 64;
#pragma unroll
        for (int i = 0; i < 16; ++i) {
            int kr = i * 4 + (l >> 4), nc = (l & 15) * 4;
            float4 v = *reinterpret_cast<const float4*>(&src[(size_t)(k0 + kr) * N + n0 + nc]);
            trans[w][nc + 0][kr] = f2b(v.x);
            trans[w][nc + 1][kr] = f2b(v.y);
            trans[w][nc + 2][kr] = f2b(v.z);
            trans[w][nc + 3][kr] = f2b(v.w);
        }
        __syncthreads();
#pragma unroll
        for (int i = 0; i < 8; ++i) {
            int nr = i * 8 + (l >> 3), c0 = (l & 7) * 8;
            int4 vv = *reinterpret_cast<const int4*>(&trans[w][nr][c0]);
            *reinterpret_cast<int4*>(&dst[(size_t)(n0 + nr) * K + k0 + c0]) = vv;
        }
        return;
    }
    int bid = blockIdx.x - 16;   // 0..1343
    int c = threadIdx.x, cc = c & 127;
    if (bid < 1024) {
        const float* pr = pe2 + bid * 128;
        const float* w = (c < 128) ? q1w : q2w;
        float acc = (c < 128) ? q1b[cc] : q2b[cc];
        for (int k = 0; k < 128; ++k) acc += pr[k] * w[k * 128 + cc];
        peq[bid * 256 + c] = acc;
    } else if (bid < 1280) {
        int tok = bid - 1024;
        const float* pr = pe3 + tok * 128;
        float acc;
        if (c < 128) {
            acc = k1b[cc];
            for (int k = 0; k < 128; ++k) acc += pr[k] * k1w[k * 128 + cc];
        } else acc = v1b[cc];
        pekv3[tok * 256 + c] = acc;
    } else {
        int tok = bid - 1280;
        const float* pr = pe4 + tok * 128;
        float acc;
        if (c < 128) {
            acc = k2b[cc];
            for (int k = 0; k < 128; ++k) acc += pr[k] * k2w[k * 128 + cc];
        } else acc = v2b[cc];
        pekv4[tok * 256 + c] = acc;
    }
}

// ---- kv path (both f3 and f4 in one launch), W-frag prefetch --------------
__global__ __launch_bounds__(256) void kv_both(
    const float* __restrict__ f3, const float* __restrict__ f4,
    const float* __restrict__ ln2w, const float* __restrict__ ln2b,
    const float* __restrict__ ln3w, const float* __restrict__ ln3b,
    const ushort* __restrict__ Wkv3t, const ushort* __restrict__ Wkv4t,
    const float* __restrict__ pekv3, const float* __restrict__ pekv4,
    ushort* __restrict__ kst3, ushort* __restrict__ vst3,
    ushort* __restrict__ kst4, ushort* __restrict__ vst4)
{
    __shared__ ushort xn[32][136];
    __shared__ ushort trans[4][64][40];
    const float* x; const float* lnw; const float* lnb; const ushort* Wt; const float* pekv;
    ushort* kst; ushort* vst; int ntok, ntok_shift; long base;
    if (blockIdx.x < 1024) {
        x = f3; lnw = ln2w; lnb = ln2b; Wt = Wkv3t; pekv = pekv3;
        kst = kst3; vst = vst3; ntok = NN3; ntok_shift = 8;
        base = (long)blockIdx.x * 32;
    } else {
        x = f4; lnw = ln3w; lnb = ln3b; Wt = Wkv4t; pekv = pekv4;
        kst = kst4; vst = vst4; ntok = NN4; ntok_shift = 6;
        base = (long)(blockIdx.x - 1024) * 32;
    }
    int t = threadIdx.x;
    int w = t >> 6, l = t & 63, l15 = l & 15, rg = l >> 4;
    // prefetch all 16 W fragments (L2-resident) before the LN phase+barrier
    bf16x8 wf[4][4];
#pragma unroll
    for (int kc = 0; kc < 4; ++kc)
#pragma unroll
        for (int nt = 0; nt < 4; ++nt)
            wf[kc][nt] = *reinterpret_cast<const bf16x8*>(
                &Wt[(size_t)(w * 64 + nt * 16 + l15) * 128 + kc * 32 + rg * 8]);
    ln_stage<136>(x, base, lnw, lnb, xn, t);
    __syncthreads();
    f32x4 acc[2][4];
#pragma unroll
    for (int m = 0; m < 2; ++m)
#pragma unroll
        for (int n = 0; n < 4; ++n) acc[m][n] = (f32x4){0.f, 0.f, 0.f, 0.f};
#pragma unroll
    for (int kc = 0; kc < 4; ++kc) {
        bf16x8 a0 = *reinterpret_cast<const bf16x8*>(&xn[l15][kc * 32 + rg * 8]);
        bf16x8 a1 = *reinterpret_cast<const bf16x8*>(&xn[16 + l15][kc * 32 + rg * 8]);
#pragma unroll
        for (int nt = 0; nt < 4; ++nt) {
            acc[0][nt] = MFMA(a0, wf[kc][nt], acc[0][nt]);
            acc[1][nt] = MFMA(a1, wf[kc][nt], acc[1][nt]);
        }
    }
    float val[2][4][4];
#pragma unroll
    for (int mt = 0; mt < 2; ++mt)
#pragma unroll
        for (int j = 0; j < 4; ++j) {
            int row = mt * 16 + rg * 4 + j;
            int tok = (int)((base + row) & (ntok - 1));
#pragma unroll
            for (int nt = 0; nt < 4; ++nt) {
                int col = w * 64 + nt * 16 + l15;
                val[mt][nt][j] = acc[mt][nt][j] + pekv[tok * 256 + col];
            }
        }
    if (w < 2) {  // channel softmax within each head (64 cols = this wave)
#pragma unroll
        for (int mt = 0; mt < 2; ++mt)
#pragma unroll
            for (int j = 0; j < 4; ++j) {
                float mx = val[mt][0][j];
#pragma unroll
                for (int nt = 1; nt < 4; ++nt) mx = fmaxf(mx, val[mt][nt][j]);
#pragma unroll
                for (int m = 1; m <= 8; m <<= 1) mx = fmaxf(mx, __shfl_xor(mx, m, 64));
                float e[4], se = 0.f;
#pragma unroll
                for (int nt = 0; nt < 4; ++nt) { e[nt] = __expf(val[mt][nt][j] - mx); se += e[nt]; }
#pragma unroll
                for (int m = 1; m <= 8; m <<= 1) se += __shfl_xor(se, m, 64);
                float inv = 1.f / se;
#pragma unroll
                for (int nt = 0; nt < 4; ++nt) val[mt][nt][j] = e[nt] * inv;
            }
    }
#pragma unroll
    for (int mt = 0; mt < 2; ++mt)
#pragma unroll
        for (int nt = 0; nt < 4; ++nt)
#pragma unroll
            for (int j = 0; j < 4; ++j)
                trans[w][nt * 16 + l15][mt * 16 + rg * 4 + j] = f2b(val[mt][nt][j]);
    __syncthreads();
    ushort* dst = (w < 2) ? kst : vst;
    int h = w & 1;
    int b = (int)(base >> ntok_shift);
    int tok0 = (int)(base & (ntok - 1));
    long o = (((long)(b * 2 + h) * 64 + l) * ntok + tok0);
    const int4* src = reinterpret_cast<const int4*>(&trans[w][l][0]);
    int4* dp = reinterpret_cast<int4*>(&dst[o]);
#pragma unroll
    for (int i = 0; i < 4; ++i) dp[i] = src[i];
}

// ------- q path (64 rows, 512 thr, 32KB aliased LDS), Wqt prefetch ---------
__global__ __launch_bounds__(512, 4) void q_mfma(
    const float* __restrict__ f2, const float* __restrict__ lnw, const float* __restrict__ lnb,
    const ushort* __restrict__ Wqt, const float* __restrict__ peq,
    ushort* __restrict__ qexp, float* __restrict__ partial)
{
    __shared__ __align__(16) char smem[32768];
    char* XN = smem + 16384;   // xn, 64 x 256B swizzled (upper half)
    char* QT = smem;           // qt, 64 x 512B swizzled (whole smem; xn dead by then)
    int t = threadIdx.x;
    long base = (long)blockIdx.x * 64;
    int w = t >> 6, l = t & 63, l15 = l & 15, rg = l >> 4;
    // prefetch Wqt fragments (L2-resident) before the LN phase+barrier
    bf16x8 wqf[4][2];
#pragma unroll
    for (int kc = 0; kc < 4; ++kc)
#pragma unroll
        for (int nt = 0; nt < 2; ++nt)
            wqf[kc][nt] = *reinterpret_cast<const bf16x8*>(
                &Wqt[(size_t)(w * 32 + nt * 16 + l15) * 128 + kc * 32 + rg * 8]);
    ln_stage_s(f2, base, lnw, lnb, XN, t);
    __syncthreads();
    f32x4 acc[4][2];
#pragma unroll
    for (int m = 0; m < 4; ++m)
#pragma unroll
        for (int n = 0; n < 2; ++n) acc[m][n] = (f32x4){0.f, 0.f, 0.f, 0.f};
#pragma unroll
    for (int kc = 0; kc < 4; ++kc) {
        bf16x8 a[4];
#pragma unroll
        for (int m = 0; m < 4; ++m)
            a[m] = *reinterpret_cast<const bf16x8*>(swad(XN, m * 16 + l15, (kc * 32 + rg * 8) * 2, 256));
#pragma unroll
        for (int nt = 0; nt < 2; ++nt)
#pragma unroll
            for (int m = 0; m < 4; ++m) acc[m][nt] = MFMA(a[m], wqf[kc][nt], acc[m][nt]);
    }
    __syncthreads();   // all XN reads done; QT may now overwrite whole smem
    float esum[2] = {0.f, 0.f};
#pragma unroll
    for (int m = 0; m < 4; ++m)
#pragma unroll
        for (int j = 0; j < 4; ++j) {
            int row = m * 16 + rg * 4 + j;
            int tok = (int)((base + row) & (NN2 - 1));
#pragma unroll
            for (int nt = 0; nt < 2; ++nt) {
                int col = w * 32 + nt * 16 + l15;
                float e = __expf(acc[m][nt][j] + peq[tok * 256 + col]);
                *reinterpret_cast<ushort*>(swad(QT, row, col * 2, 512)) = f2b(e);
                esum[nt] += e;
            }
        }
#pragma unroll
    for (int nt = 0; nt < 2; ++nt) {
        esum[nt] += __shfl_xor(esum[nt], 16, 64);
        esum[nt] += __shfl_xor(esum[nt], 32, 64);
    }
    if (rg == 0) {
        int bidx = blockIdx.x >> 4, chunk = blockIdx.x & 15;
#pragma unroll
        for (int nt = 0; nt < 2; ++nt)
            partial[(size_t)(bidx * 16 + chunk) * 256 + w * 32 + nt * 16 + l15] = esum[nt];
    }
    __syncthreads();
    {
        int r = t >> 3, c0 = (t & 7) * 64;   // byte col
        char* dst = (char*)qexp + (base + r) * 512 + c0;
#pragma unroll
        for (int i = 0; i < 4; ++i) {
            int4 vv = *reinterpret_cast<const int4*>(swad(QT, r, c0 + i * 16, 512));
            *reinterpret_cast<int4*>(dst + i * 16) = vv;
        }
    }
}

// ---- fused: per-wave ctx (head w) -> 1/sum scale -> rp GEMM -> MbT --------
__global__ __launch_bounds__(256) void ctx_rp(
    const ushort* __restrict__ kst3, const ushort* __restrict__ vst3,
    const ushort* __restrict__ kst4, const ushort* __restrict__ vst4,
    const float* __restrict__ partial, const ushort* __restrict__ RpT,
    ushort* __restrict__ MbT)
{
    __shared__ float rsv[256];
    __shared__ __align__(16) char ctile[4][64 * 128];   // per-head 64 x 128B swizzled
    int b = blockIdx.x, t = threadIdx.x;
    int w = t >> 6, l = t & 63, l15 = l & 15, rg = l >> 4;  // w = head g
    // reduce token-softmax partials -> 1/sum
    {
        float s = 0.f;
        for (int ch = 0; ch < 16; ++ch) s += partial[((size_t)b * 16 + ch) * 256 + t];
        rsv[t] = 1.f / s;
    }
    // ctx for head g = w : C[d][e] = sum_tok ks[d][tok]*vs[e][tok]
    const ushort* ks; const ushort* vs; int ntok;
    if (w < 2) { ntok = 256; ks = kst3 + (long)(b * 2 + w) * 64 * 256; vs = vst3 + (long)(b * 2 + w) * 64 * 256; }
    else       { ntok = 64;  ks = kst4 + (long)(b * 2 + (w - 2)) * 64 * 64; vs = vst4 + (long)(b * 2 + (w - 2)) * 64 * 64; }
    f32x4 acc[4][4];
#pragma unroll
    for (int m = 0; m < 4; ++m)
#pragma unroll
        for (int n = 0; n < 4; ++n) acc[m][n] = (f32x4){0.f, 0.f, 0.f, 0.f};
    for (int kc = 0; kc < (ntok >> 5); ++kc) {
        bf16x8 a[4];
#pragma unroll
        for (int mt = 0; mt < 4; ++mt)
            a[mt] = *reinterpret_cast<const bf16x8*>(&ks[(size_t)(mt * 16 + l15) * ntok + kc * 32 + rg * 8]);
#pragma unroll
        for (int nt = 0; nt < 4; ++nt) {
            bf16x8 bfr = *reinterpret_cast<const bf16x8*>(&vs[(size_t)(nt * 16 + l15) * ntok + kc * 32 + rg * 8]);
#pragma unroll
            for (int mt = 0; mt < 4; ++mt) acc[mt][nt] = MFMA(a[mt], bfr, acc[mt][nt]);
        }
    }
    __syncthreads();   // rsv ready
    // scale rows (d-axis) by 1/sum, write bf16 -> ctile (swizzled transpose)
#pragma unroll
    for (int mt = 0; mt < 4; ++mt)
#pragma unroll
        for (int j = 0; j < 4; ++j) {
            int row = mt * 16 + rg * 4 + j;
            float sc = rsv[w * 64 + row];
#pragma unroll
            for (int nt = 0; nt < 4; ++nt)
                *reinterpret_cast<ushort*>(swad(ctile[w], row, (nt * 16 + l15) * 2, 128))
                    = f2b(acc[mt][nt][j] * sc);
        }
    __syncthreads();
    // rp GEMM: Mb[n][g*64+d] = sum_e ctx'[d][e] * rp[g*64+e][n]
    bf16x8 a2[4][2];
#pragma unroll
    for (int m = 0; m < 4; ++m)
#pragma unroll
        for (int kc = 0; kc < 2; ++kc)
            a2[m][kc] = *reinterpret_cast<const bf16x8*>(
                swad(ctile[w], m * 16 + l15, (kc * 32 + rg * 8) * 2, 128));
#pragma unroll
    for (int nt = 0; nt < 8; ++nt) {
        f32x4 acc2[4];
#pragma unroll
        for (int m = 0; m < 4; ++m) acc2[m] = (f32x4){0.f, 0.f, 0.f, 0.f};
#pragma unroll
        for (int kc = 0; kc < 2; ++kc) {
            bf16x8 bfr = *reinterpret_cast<const bf16x8*>(
                &RpT[(size_t)(nt * 16 + l15) * 256 + w * 64 + kc * 32 + rg * 8]);
#pragma unroll
            for (int m = 0; m < 4; ++m) acc2[m] = MFMA(a2[m][kc], bfr, acc2[m]);
        }
        int n = nt * 16 + l15;
#pragma unroll
        for (int m = 0; m < 4; ++m) {
            unsigned int u0 = (unsigned int)f2b(acc2[m][0]) | ((unsigned int)f2b(acc2[m][1]) << 16);
            unsigned int u1 = (unsigned int)f2b(acc2[m][2]) | ((unsigned int)f2b(acc2[m][3]) << 16);
            uint2 uu; uu.x = u0; uu.y = u1;
            *reinterpret_cast<uint2*>(&MbT[((long)b * 128 + n) * 256 + w * 64 + m * 16 + rg * 4]) = uu;
        }
    }
}

// ---- fused (128 rows, 512 thr, 64KB LDS -> 2 blk/CU), dual-buffer phase B
//      + software-pipelined W fragments; barriers amortized over 2x rows
__global__ __launch_bounds__(512, 2) void attn_mlp(
    const ushort* __restrict__ qexp, const ushort* __restrict__ MbT,
    const float* __restrict__ rpb, const float* __restrict__ f2,
    const float* __restrict__ lnw, const float* __restrict__ lnb,
    const ushort* __restrict__ W1t, const float* __restrict__ ff1b,
    const ushort* __restrict__ W2t, const float* __restrict__ ff2b,
    float* __restrict__ out)
{
    __shared__ __align__(16) char smem[65536];
    char* XN = smem;            // qexp h1 stage -> xn (128 x 256B swizzled)
    char* R2 = smem + 32768;    // qexp h0 stage -> LN stats -> hid quarter (128 x 256B swz)
    float* Ps = reinterpret_cast<float*>(R2);                 // [128][8] row sums
    float* Pq = reinterpret_cast<float*>(R2 + 4096);          // [128][8] row sumsq
    float* MR = reinterpret_cast<float*>(R2 + 8192);          // [128] mean
    float* RR = reinterpret_cast<float*>(R2 + 8704);          // [128] rstd
    int t = threadIdx.x;
    long base = (long)blockIdx.x * 128;
    int b = blockIdx.x >> 3;
    int w = t >> 6, l = t & 63, l15 = l & 15, rg = l >> 4;
    int col = w * 16 + l15;

    // -------- prefetch: both qexp halves (128 rows) + Mb B-frags -----------
    int sr = t >> 2, sc = (t & 3) * 64;          // 128 rows x 64B per thread
    const char* qsrc = (const char*)qexp + (base + sr) * 512 + sc;
    int4 q0h[4], q1h[4];
#pragma unroll
    for (int i = 0; i < 4; ++i) {
        q0h[i] = *reinterpret_cast<const int4*>(qsrc + i * 16);
        q1h[i] = *reinterpret_cast<const int4*>(qsrc + 256 + i * 16);
    }
    const ushort* mb = MbT + (long)b * 128 * 256;
    bf16x8 mbfr[8];
#pragma unroll
    for (int kc2 = 0; kc2 < 8; ++kc2)
        mbfr[kc2] = *reinterpret_cast<const bf16x8*>(&mb[(size_t)col * 256 + kc2 * 32 + rg * 8]);

    // Phase B': stage BOTH halves (h0->R2, h1->XN), one barrier, 64 MFMAs
#pragma unroll
    for (int i = 0; i < 4; ++i) {
        *reinterpret_cast<int4*>(swad(R2, sr, sc + i * 16, 256)) = q0h[i];
        *reinterpret_cast<int4*>(swad(XN, sr, sc + i * 16, 256)) = q1h[i];
    }
    __syncthreads();
    f32x4 accC[8];
#pragma unroll
    for (int m = 0; m < 8; ++m) accC[m] = (f32x4){0.f, 0.f, 0.f, 0.f};
#pragma unroll
    for (int kc2 = 0; kc2 < 8; ++kc2) {
        char* buf = (kc2 < 4) ? R2 : XN;
        int kc = kc2 & 3;
#pragma unroll
        for (int m = 0; m < 8; ++m) {
            bf16x8 a = *reinterpret_cast<const bf16x8*>(
                swad(buf, m * 16 + l15, (kc * 32 + rg * 8) * 2, 256));
            accC[m] = MFMA(a, mbfr[kc2], accC[m]);
        }
    }
    __syncthreads();   // all qexp reads done; R2/XN reusable

    // residual x = f2 + attn + rpb -> xres regs; LN partials via shfl -> Ps/Pq
    float xres[8][4];
    {
        float bias = rpb[col];
#pragma unroll
        for (int m = 0; m < 8; ++m)
#pragma unroll
            for (int j = 0; j < 4; ++j) {
                int row = m * 16 + rg * 4 + j;
                float xv = f2[(base + row) * 128 + col] + accC[m][j] + bias;
                xres[m][j] = xv;
                float s = xv, q = xv * xv;
#pragma unroll
                for (int msk = 1; msk <= 8; msk <<= 1) {
                    s += __shfl_xor(s, msk, 64);
                    q += __shfl_xor(q, msk, 64);
                }
                if (l15 == 0) { Ps[row * 8 + w] = s; Pq[row * 8 + w] = q; }
            }
    }
    __syncthreads();
    if (t < 128) {
        float4 s0 = *reinterpret_cast<float4*>(&Ps[t * 8]);
        float4 s1 = *reinterpret_cast<float4*>(&Ps[t * 8 + 4]);
        float4 q0 = *reinterpret_cast<float4*>(&Pq[t * 8]);
        float4 q1 = *reinterpret_cast<float4*>(&Pq[t * 8 + 4]);
        float s = s0.x + s0.y + s0.z + s0.w + s1.x + s1.y + s1.z + s1.w;
        float q = q0.x + q0.y + q0.z + q0.w + q1.x + q1.y + q1.z + q1.w;
        float mean = s * (1.f / 128.f);
        float var = q * (1.f / 128.f) - mean * mean;
        MR[t] = mean;
        RR[t] = rsqrtf(var + EPSF);
    }
    __syncthreads();
    {
        float lw = lnw[col], lb = lnb[col];
#pragma unroll
        for (int m = 0; m < 8; ++m)
#pragma unroll
            for (int j = 0; j < 4; ++j) {
                int row = m * 16 + rg * 4 + j;
                float o = (xres[m][j] - MR[row]) * RR[row] * lw + lb;
                *reinterpret_cast<ushort*>(swad(XN, row, col * 2, 256)) = f2b(o);
            }
    }
    __syncthreads();   // MR/RR consumed; R2 free for hid

    // MLP K-quartered with software-pipelined W fragments over 128 rows
    f32x4 accF[8];
#pragma unroll
    for (int m = 0; m < 8; ++m) accF[m] = (f32x4){0.f, 0.f, 0.f, 0.f};
    bf16x8 w1f[4], w2f[4];
#pragma unroll
    for (int kc = 0; kc < 4; ++kc)
        w1f[kc] = *reinterpret_cast<const bf16x8*>(&W1t[(size_t)col * 128 + kc * 32 + rg * 8]);
#pragma unroll
    for (int q = 0; q < 4; ++q) {
        // prefetch W2 frags for F(q) (consumed after next barrier)
#pragma unroll
        for (int kc = 0; kc < 4; ++kc)
            w2f[kc] = *reinterpret_cast<const bf16x8*>(
                &W2t[(size_t)col * 512 + q * 128 + kc * 32 + rg * 8]);
        // E(q): xn @ W1(q) + gelu -> R2
        {
            f32x4 acc[8];
#pragma unroll
            for (int m = 0; m < 8; ++m) acc[m] = (f32x4){0.f, 0.f, 0.f, 0.f};
#pragma unroll
            for (int kc = 0; kc < 4; ++kc)
#pragma unroll
                for (int m = 0; m < 8; ++m) {
                    bf16x8 a = *reinterpret_cast<const bf16x8*>(
                        swad(XN, m * 16 + l15, (kc * 32 + rg * 8) * 2, 256));
                    acc[m] = MFMA(a, w1f[kc], acc[m]);
                }
            float b1 = ff1b[q * 128 + col];
#pragma unroll
            for (int m = 0; m < 8; ++m)
#pragma unroll
                for (int j = 0; j < 4; ++j)
                    *reinterpret_cast<ushort*>(swad(R2, m * 16 + rg * 4 + j, col * 2, 256))
                        = f2b(gelu_f(acc[m][j] + b1));
        }
        __syncthreads();
        // prefetch W1 frags for E(q+1)
        if (q < 3) {
#pragma unroll
            for (int kc = 0; kc < 4; ++kc)
                w1f[kc] = *reinterpret_cast<const bf16x8*>(
                    &W1t[(size_t)((q + 1) * 128 + col) * 128 + kc * 32 + rg * 8]);
        }
        // F(q): hid @ W2(q) accumulate
#pragma unroll
        for (int kc = 0; kc < 4; ++kc)
#pragma unroll
            for (int m = 0; m < 8; ++m) {
                bf16x8 a = *reinterpret_cast<const bf16x8*>(
                    swad(R2, m * 16 + l15, (kc * 32 + rg * 8) * 2, 256));
                accF[m] = MFMA(a, w2f[kc], accF[m]);
            }
        if (q < 3) __syncthreads();
    }
    // epilogue: out = x + mlp + b2
    {
        float b2 = ff2b[col];
#pragma unroll
        for (int m = 0; m < 8; ++m)
#pragma unroll
            for (int j = 0; j < 4; ++j) {
                int row = m * 16 + rg * 4 + j;
                long g = (base + row) * 128 + col;
                out[g] = xres[m][j] + accF[m][j] + b2;
            }
    }
}

extern "C" void kernel_launch(void* const* d_in, const int* in_sizes, int n_in,
                              void* d_out, int out_size, void* d_ws, size_t ws_size,
                              hipStream_t stream) {
    const float* f2   = (const float*)d_in[0];
    const float* f3   = (const float*)d_in[1];
    const float* f4   = (const float*)d_in[2];
    const float* pe2  = (const float*)d_in[3];
    const float* pe3  = (const float*)d_in[4];
    const float* pe4  = (const float*)d_in[5];
    const float* ln1w = (const float*)d_in[6];
    const float* ln1b = (const float*)d_in[7];
    const float* ln2w = (const float*)d_in[8];
    const float* ln2b = (const float*)d_in[9];
    const float* ln3w = (const float*)d_in[10];
    const float* ln3b = (const float*)d_in[11];
    const float* ln4w = (const float*)d_in[12];
    const float* ln4b = (const float*)d_in[13];
    const float* q1w  = (const float*)d_in[14];
    const float* q1b  = (const float*)d_in[15];
    const float* k1w  = (const float*)d_in[16];
    const float* k1b  = (const float*)d_in[17];
    const float* v1w  = (const float*)d_in[18];
    const float* v1b  = (const float*)d_in[19];
    const float* q2w  = (const float*)d_in[20];
    const float* q2b  = (const float*)d_in[21];
    const float* k2w  = (const float*)d_in[22];
    const float* k2b  = (const float*)d_in[23];
    const float* v2w  = (const float*)d_in[24];
    const float* v2b  = (const float*)d_in[25];
    const float* rpw  = (const float*)d_in[26];
    const float* rpb  = (const float*)d_in[27];
    const float* ff1w = (const float*)d_in[28];
    const float* ff1b = (const float*)d_in[29];
    const float* ff2w = (const float*)d_in[30];
    const float* ff2b = (const float*)d_in[31];

    char* ws = (char*)d_ws;
    size_t off = 0;
    ushort* qexp  = (ushort*)(ws + off); off += (size_t)BB * NN2 * 256 * 2;
    ushort* kst3  = (ushort*)(ws + off); off += (size_t)BB * 2 * 64 * NN3 * 2;
    ushort* vst3  = (ushort*)(ws + off); off += (size_t)BB * 2 * 64 * NN3 * 2;
    ushort* kst4  = (ushort*)(ws + off); off += (size_t)BB * 2 * 64 * NN4 * 2;
    ushort* vst4  = (ushort*)(ws + off); off += (size_t)BB * 2 * 64 * NN4 * 2;
    ushort* MbT   = (ushort*)(ws + off); off += (size_t)BB * 128 * 256 * 2;
    ushort* Wqt   = (ushort*)(ws + off); off += 256 * 128 * 2;
    ushort* Wkv3t = (ushort*)(ws + off); off += 256 * 128 * 2;
    ushort* Wkv4t = (ushort*)(ws + off); off += 256 * 128 * 2;
    ushort* W1t   = (ushort*)(ws + off); off += 512 * 128 * 2;
    ushort* W2t   = (ushort*)(ws + off); off += 128 * 512 * 2;
    ushort* RpT   = (ushort*)(ws + off); off += 128 * 256 * 2;
    float*  peq   = (float*)(ws + off);  off += (size_t)NN2 * 256 * 4;
    float*  pekv3 = (float*)(ws + off);  off += (size_t)NN3 * 256 * 4;
    float*  pekv4 = (float*)(ws + off);  off += (size_t)NN4 * 256 * 4;
    float*  partial = (float*)(ws + off); off += (size_t)BB * 16 * 256 * 4;

    prep_all<<<16 + 1344, 256, 0, stream>>>(q1w, q2w, k1w, v1w, k2w, v2w, ff1w, ff2w, rpw,
                                            pe2, pe3, pe4, q1b, q2b, k1b, v1b, k2b, v2b,
                                            Wqt, Wkv3t, Wkv4t, W1t, W2t, RpT,
                                            peq, pekv3, pekv4);
    kv_both<<<1280, 256, 0, stream>>>(f3, f4, ln2w, ln2b, ln3w, ln3b, Wkv3t, Wkv4t,
                                      pekv3, pekv4, kst3, vst3, kst4, vst4);
    q_mfma<<<BB * NN2 / 64, 512, 0, stream>>>(f2, ln1w, ln1b, Wqt, peq, qexp, partial);
    ctx_rp<<<BB, 256, 0, stream>>>(kst3, vst3, kst4, vst4, partial, RpT, MbT);
    attn_mlp<<<BB * NN2 / 128, 512, 0, stream>>>(qexp, MbT, rpb, f2,
                                                 ln4w, ln4b, W1t, ff1b, W2t, ff2b, (float*)d_out);
}

// Round 22
// 210.236 us; speedup vs baseline: 1.1766x; 1.1766x over previous
//
#include <hip/hip_runtime.h>
#include <hip/hip_bf16.h>
#include <math.h>

#define BB 128
#define NN2 1024
#define NN3 256
#define NN4 64
#define DD 128
#define MLPD 512
#define EPSF 1e-5f

typedef short bf16x8 __attribute__((ext_vector_type(8)));
typedef float f32x4 __attribute__((ext_vector_type(4)));

__device__ inline ushort f2b(float x) {
    __hip_bfloat16 h = __float2bfloat16(x);
    return __builtin_bit_cast(ushort, h);
}
__device__ inline float b2f(ushort u) {
    unsigned int v = ((unsigned int)u) << 16;
    return __builtin_bit_cast(float, v);
}
// tanh-form GELU via exp
__device__ inline float gelu_f(float u) {
    float t = 0.7978845608f * u + 0.0356774081f * (u * u * u);
    float e = __expf(2.f * t);
    return u - u * __builtin_amdgcn_rcpf(e + 1.f);
}

#define MFMA(a, b, c) __builtin_amdgcn_mfma_f32_16x16x32_bf16((a), (b), (c), 0, 0, 0)

// XOR-swizzled LDS tile addressing: byte ^= (row*16) & (stride-16).
__device__ inline char* swad(char* base, int row, int bytecol, int strideB) {
    return base + (size_t)row * strideB + ((bytecol) ^ ((row << 4) & (strideB - 16)));
}

// LN of rows (8 threads/row) from global -> bf16 LDS tile [rows][STRIDE]
template <int STRIDE>
__device__ inline void ln_stage(const float* __restrict__ x, long base,
                                const float* __restrict__ w, const float* __restrict__ b,
                                ushort xn[][STRIDE], int t)
{
    int r = t >> 3, l8 = t & 7;
    const float4* xr4 = reinterpret_cast<const float4*>(x + (base + r) * DD);
    float4 v[4];
#pragma unroll
    for (int j = 0; j < 4; ++j) v[j] = xr4[l8 * 4 + j];
    float s = 0.f;
#pragma unroll
    for (int j = 0; j < 4; ++j) s += v[j].x + v[j].y + v[j].z + v[j].w;
#pragma unroll
    for (int m = 1; m <= 4; m <<= 1) s += __shfl_xor(s, m, 64);
    float mean = s * (1.f / 128.f);
    float s2 = 0.f;
#pragma unroll
    for (int j = 0; j < 4; ++j) {
        v[j].x -= mean; v[j].y -= mean; v[j].z -= mean; v[j].w -= mean;
        s2 += v[j].x * v[j].x + v[j].y * v[j].y + v[j].z * v[j].z + v[j].w * v[j].w;
    }
#pragma unroll
    for (int m = 1; m <= 4; m <<= 1) s2 += __shfl_xor(s2, m, 64);
    float rstd = rsqrtf(s2 * (1.f / 128.f) + EPSF);
    int c0 = l8 * 16;
#pragma unroll
    for (int j = 0; j < 4; ++j) {
        int c = c0 + j * 4;
        float o0 = v[j].x * rstd * w[c] + b[c];
        float o1 = v[j].y * rstd * w[c + 1] + b[c + 1];
        float o2 = v[j].z * rstd * w[c + 2] + b[c + 2];
        float o3 = v[j].w * rstd * w[c + 3] + b[c + 3];
        uint2 uu;
        uu.x = (unsigned int)f2b(o0) | ((unsigned int)f2b(o1) << 16);
        uu.y = (unsigned int)f2b(o2) | ((unsigned int)f2b(o3) << 16);
        *reinterpret_cast<uint2*>(&xn[r][c]) = uu;
    }
}

// LN (8 threads/row) from global -> swizzled bf16 LDS tile (256B stride)
__device__ inline void ln_stage_s(const float* __restrict__ x, long base,
                                  const float* __restrict__ w, const float* __restrict__ b,
                                  char* R, int t)
{
    int r = t >> 3, l8 = t & 7;
    const float4* xr4 = reinterpret_cast<const float4*>(x + (base + r) * DD);
    float4 v[4];
#pragma unroll
    for (int j = 0; j < 4; ++j) v[j] = xr4[l8 * 4 + j];
    float s = 0.f;
#pragma unroll
    for (int j = 0; j < 4; ++j) s += v[j].x + v[j].y + v[j].z + v[j].w;
#pragma unroll
    for (int m = 1; m <= 4; m <<= 1) s += __shfl_xor(s, m, 64);
    float mean = s * (1.f / 128.f);
    float s2 = 0.f;
#pragma unroll
    for (int j = 0; j < 4; ++j) {
        v[j].x -= mean; v[j].y -= mean; v[j].z -= mean; v[j].w -= mean;
        s2 += v[j].x * v[j].x + v[j].y * v[j].y + v[j].z * v[j].z + v[j].w * v[j].w;
    }
#pragma unroll
    for (int m = 1; m <= 4; m <<= 1) s2 += __shfl_xor(s2, m, 64);
    float rstd = rsqrtf(s2 * (1.f / 128.f) + EPSF);
    int c0 = l8 * 16;
#pragma unroll
    for (int j = 0; j < 4; ++j) {
        int c = c0 + j * 4;
        float o0 = v[j].x * rstd * w[c] + b[c];
        float o1 = v[j].y * rstd * w[c + 1] + b[c + 1];
        float o2 = v[j].z * rstd * w[c + 2] + b[c + 2];
        float o3 = v[j].w * rstd * w[c + 3] + b[c + 3];
        uint2 uu;
        uu.x = (unsigned int)f2b(o0) | ((unsigned int)f2b(o1) << 16);
        uu.y = (unsigned int)f2b(o2) | ((unsigned int)f2b(o3) << 16);
        *reinterpret_cast<uint2*>(swad(R, r, c * 2, 256)) = uu;
    }
}

// -------- merged prep: blocks 0-15 weight transpose; 16.. pe@W folds (fp32)
__global__ __launch_bounds__(256) void prep_all(
    const float* __restrict__ q1w, const float* __restrict__ q2w,
    const float* __restrict__ k1w, const float* __restrict__ v1w,
    const float* __restrict__ k2w, const float* __restrict__ v2w,
    const float* __restrict__ ff1w, const float* __restrict__ ff2w,
    const float* __restrict__ rpw,
    const float* __restrict__ pe2, const float* __restrict__ pe3, const float* __restrict__ pe4,
    const float* __restrict__ q1b, const float* __restrict__ q2b,
    const float* __restrict__ k1b, const float* __restrict__ v1b,
    const float* __restrict__ k2b, const float* __restrict__ v2b,
    ushort* __restrict__ Wqt, ushort* __restrict__ Wkv3t, ushort* __restrict__ Wkv4t,
    ushort* __restrict__ W1t, ushort* __restrict__ W2t, ushort* __restrict__ RpT,
    float* __restrict__ peq, float* __restrict__ pekv3, float* __restrict__ pekv4)
{
    __shared__ ushort trans[4][64][88];
    if (blockIdx.x < 16) {
        int w = threadIdx.x >> 6, l = threadIdx.x & 63;
        int tile = blockIdx.x * 4 + w;  // 0..63
        const float* src; ushort* dst; int K, N, tk, tn;
        if (tile < 24) {
            int job = tile >> 2, rel = tile & 3;
            K = 128; N = 128; tk = rel >> 1; tn = rel & 1;
            if      (job == 0) { src = q1w; dst = Wqt; }
            else if (job == 1) { src = q2w; dst = Wqt + 16384; }
            else if (job == 2) { src = k1w; dst = Wkv3t; }
            else if (job == 3) { src = v1w; dst = Wkv3t + 16384; }
            else if (job == 4) { src = k2w; dst = Wkv4t; }
            else               { src = v2w; dst = Wkv4t + 16384; }
        } else if (tile < 40) {
            int rel = tile - 24; src = ff1w; dst = W1t; K = 128; N = 512; tk = rel >> 3; tn = rel & 7;
        } else if (tile < 56) {
            int rel = tile - 40; src = ff2w; dst = W2t; K = 512; N = 128; tk = rel >> 1; tn = rel & 1;
        } else {
            int rel = tile - 56; src = rpw; dst = RpT; K = 256; N = 128; tk = rel >> 1; tn = rel & 1;
        }
        int k0 = tk * 64, n0 = tn * 64;
#pragma unroll
        for (int i = 0; i < 16; ++i) {
            int kr = i * 4 + (l >> 4), nc = (l & 15) * 4;
            float4 v = *reinterpret_cast<const float4*>(&src[(size_t)(k0 + kr) * N + n0 + nc]);
            trans[w][nc + 0][kr] = f2b(v.x);
            trans[w][nc + 1][kr] = f2b(v.y);
            trans[w][nc + 2][kr] = f2b(v.z);
            trans[w][nc + 3][kr] = f2b(v.w);
        }
        __syncthreads();
#pragma unroll
        for (int i = 0; i < 8; ++i) {
            int nr = i * 8 + (l >> 3), c0 = (l & 7) * 8;
            int4 vv = *reinterpret_cast<const int4*>(&trans[w][nr][c0]);
            *reinterpret_cast<int4*>(&dst[(size_t)(n0 + nr) * K + k0 + c0]) = vv;
        }
        return;
    }
    int bid = blockIdx.x - 16;   // 0..1343
    int c = threadIdx.x, cc = c & 127;
    if (bid < 1024) {
        const float* pr = pe2 + bid * 128;
        const float* w = (c < 128) ? q1w : q2w;
        float acc = (c < 128) ? q1b[cc] : q2b[cc];
        for (int k = 0; k < 128; ++k) acc += pr[k] * w[k * 128 + cc];
        peq[bid * 256 + c] = acc;
    } else if (bid < 1280) {
        int tok = bid - 1024;
        const float* pr = pe3 + tok * 128;
        float acc;
        if (c < 128) {
            acc = k1b[cc];
            for (int k = 0; k < 128; ++k) acc += pr[k] * k1w[k * 128 + cc];
        } else acc = v1b[cc];
        pekv3[tok * 256 + c] = acc;
    } else {
        int tok = bid - 1280;
        const float* pr = pe4 + tok * 128;
        float acc;
        if (c < 128) {
            acc = k2b[cc];
            for (int k = 0; k < 128; ++k) acc += pr[k] * k2w[k * 128 + cc];
        } else acc = v2b[cc];
        pekv4[tok * 256 + c] = acc;
    }
}

// ---- kv path (both f3 and f4 in one launch), W-frag prefetch --------------
__global__ __launch_bounds__(256) void kv_both(
    const float* __restrict__ f3, const float* __restrict__ f4,
    const float* __restrict__ ln2w, const float* __restrict__ ln2b,
    const float* __restrict__ ln3w, const float* __restrict__ ln3b,
    const ushort* __restrict__ Wkv3t, const ushort* __restrict__ Wkv4t,
    const float* __restrict__ pekv3, const float* __restrict__ pekv4,
    ushort* __restrict__ kst3, ushort* __restrict__ vst3,
    ushort* __restrict__ kst4, ushort* __restrict__ vst4)
{
    __shared__ ushort xn[32][136];
    __shared__ ushort trans[4][64][40];
    const float* x; const float* lnw; const float* lnb; const ushort* Wt; const float* pekv;
    ushort* kst; ushort* vst; int ntok, ntok_shift; long base;
    if (blockIdx.x < 1024) {
        x = f3; lnw = ln2w; lnb = ln2b; Wt = Wkv3t; pekv = pekv3;
        kst = kst3; vst = vst3; ntok = NN3; ntok_shift = 8;
        base = (long)blockIdx.x * 32;
    } else {
        x = f4; lnw = ln3w; lnb = ln3b; Wt = Wkv4t; pekv = pekv4;
        kst = kst4; vst = vst4; ntok = NN4; ntok_shift = 6;
        base = (long)(blockIdx.x - 1024) * 32;
    }
    int t = threadIdx.x;
    int w = t >> 6, l = t & 63, l15 = l & 15, rg = l >> 4;
    // prefetch all 16 W fragments (L2-resident) before the LN phase+barrier
    bf16x8 wf[4][4];
#pragma unroll
    for (int kc = 0; kc < 4; ++kc)
#pragma unroll
        for (int nt = 0; nt < 4; ++nt)
            wf[kc][nt] = *reinterpret_cast<const bf16x8*>(
                &Wt[(size_t)(w * 64 + nt * 16 + l15) * 128 + kc * 32 + rg * 8]);
    ln_stage<136>(x, base, lnw, lnb, xn, t);
    __syncthreads();
    f32x4 acc[2][4];
#pragma unroll
    for (int m = 0; m < 2; ++m)
#pragma unroll
        for (int n = 0; n < 4; ++n) acc[m][n] = (f32x4){0.f, 0.f, 0.f, 0.f};
#pragma unroll
    for (int kc = 0; kc < 4; ++kc) {
        bf16x8 a0 = *reinterpret_cast<const bf16x8*>(&xn[l15][kc * 32 + rg * 8]);
        bf16x8 a1 = *reinterpret_cast<const bf16x8*>(&xn[16 + l15][kc * 32 + rg * 8]);
#pragma unroll
        for (int nt = 0; nt < 4; ++nt) {
            acc[0][nt] = MFMA(a0, wf[kc][nt], acc[0][nt]);
            acc[1][nt] = MFMA(a1, wf[kc][nt], acc[1][nt]);
        }
    }
    float val[2][4][4];
#pragma unroll
    for (int mt = 0; mt < 2; ++mt)
#pragma unroll
        for (int j = 0; j < 4; ++j) {
            int row = mt * 16 + rg * 4 + j;
            int tok = (int)((base + row) & (ntok - 1));
#pragma unroll
            for (int nt = 0; nt < 4; ++nt) {
                int col = w * 64 + nt * 16 + l15;
                val[mt][nt][j] = acc[mt][nt][j] + pekv[tok * 256 + col];
            }
        }
    if (w < 2) {  // channel softmax within each head (64 cols = this wave)
#pragma unroll
        for (int mt = 0; mt < 2; ++mt)
#pragma unroll
            for (int j = 0; j < 4; ++j) {
                float mx = val[mt][0][j];
#pragma unroll
                for (int nt = 1; nt < 4; ++nt) mx = fmaxf(mx, val[mt][nt][j]);
#pragma unroll
                for (int m = 1; m <= 8; m <<= 1) mx = fmaxf(mx, __shfl_xor(mx, m, 64));
                float e[4], se = 0.f;
#pragma unroll
                for (int nt = 0; nt < 4; ++nt) { e[nt] = __expf(val[mt][nt][j] - mx); se += e[nt]; }
#pragma unroll
                for (int m = 1; m <= 8; m <<= 1) se += __shfl_xor(se, m, 64);
                float inv = 1.f / se;
#pragma unroll
                for (int nt = 0; nt < 4; ++nt) val[mt][nt][j] = e[nt] * inv;
            }
    }
#pragma unroll
    for (int mt = 0; mt < 2; ++mt)
#pragma unroll
        for (int nt = 0; nt < 4; ++nt)
#pragma unroll
            for (int j = 0; j < 4; ++j)
                trans[w][nt * 16 + l15][mt * 16 + rg * 4 + j] = f2b(val[mt][nt][j]);
    __syncthreads();
    ushort* dst = (w < 2) ? kst : vst;
    int h = w & 1;
    int b = (int)(base >> ntok_shift);
    int tok0 = (int)(base & (ntok - 1));
    long o = (((long)(b * 2 + h) * 64 + l) * ntok + tok0);
    const int4* src = reinterpret_cast<const int4*>(&trans[w][l][0]);
    int4* dp = reinterpret_cast<int4*>(&dst[o]);
#pragma unroll
    for (int i = 0; i < 4; ++i) dp[i] = src[i];
}

// ------- q path (64 rows, 512 thr, 32KB aliased LDS), Wqt prefetch ---------
__global__ __launch_bounds__(512, 4) void q_mfma(
    const float* __restrict__ f2, const float* __restrict__ lnw, const float* __restrict__ lnb,
    const ushort* __restrict__ Wqt, const float* __restrict__ peq,
    ushort* __restrict__ qexp, float* __restrict__ partial)
{
    __shared__ __align__(16) char smem[32768];
    char* XN = smem + 16384;   // xn, 64 x 256B swizzled (upper half)
    char* QT = smem;           // qt, 64 x 512B swizzled (whole smem; xn dead by then)
    int t = threadIdx.x;
    long base = (long)blockIdx.x * 64;
    int w = t >> 6, l = t & 63, l15 = l & 15, rg = l >> 4;
    // prefetch Wqt fragments (L2-resident) before the LN phase+barrier
    bf16x8 wqf[4][2];
#pragma unroll
    for (int kc = 0; kc < 4; ++kc)
#pragma unroll
        for (int nt = 0; nt < 2; ++nt)
            wqf[kc][nt] = *reinterpret_cast<const bf16x8*>(
                &Wqt[(size_t)(w * 32 + nt * 16 + l15) * 128 + kc * 32 + rg * 8]);
    ln_stage_s(f2, base, lnw, lnb, XN, t);
    __syncthreads();
    f32x4 acc[4][2];
#pragma unroll
    for (int m = 0; m < 4; ++m)
#pragma unroll
        for (int n = 0; n < 2; ++n) acc[m][n] = (f32x4){0.f, 0.f, 0.f, 0.f};
#pragma unroll
    for (int kc = 0; kc < 4; ++kc) {
        bf16x8 a[4];
#pragma unroll
        for (int m = 0; m < 4; ++m)
            a[m] = *reinterpret_cast<const bf16x8*>(swad(XN, m * 16 + l15, (kc * 32 + rg * 8) * 2, 256));
#pragma unroll
        for (int nt = 0; nt < 2; ++nt)
#pragma unroll
            for (int m = 0; m < 4; ++m) acc[m][nt] = MFMA(a[m], wqf[kc][nt], acc[m][nt]);
    }
    __syncthreads();   // all XN reads done; QT may now overwrite whole smem
    float esum[2] = {0.f, 0.f};
#pragma unroll
    for (int m = 0; m < 4; ++m)
#pragma unroll
        for (int j = 0; j < 4; ++j) {
            int row = m * 16 + rg * 4 + j;
            int tok = (int)((base + row) & (NN2 - 1));
#pragma unroll
            for (int nt = 0; nt < 2; ++nt) {
                int col = w * 32 + nt * 16 + l15;
                float e = __expf(acc[m][nt][j] + peq[tok * 256 + col]);
                *reinterpret_cast<ushort*>(swad(QT, row, col * 2, 512)) = f2b(e);
                esum[nt] += e;
            }
        }
#pragma unroll
    for (int nt = 0; nt < 2; ++nt) {
        esum[nt] += __shfl_xor(esum[nt], 16, 64);
        esum[nt] += __shfl_xor(esum[nt], 32, 64);
    }
    if (rg == 0) {
        int bidx = blockIdx.x >> 4, chunk = blockIdx.x & 15;
#pragma unroll
        for (int nt = 0; nt < 2; ++nt)
            partial[(size_t)(bidx * 16 + chunk) * 256 + w * 32 + nt * 16 + l15] = esum[nt];
    }
    __syncthreads();
    {
        int r = t >> 3, c0 = (t & 7) * 64;   // byte col
        char* dst = (char*)qexp + (base + r) * 512 + c0;
#pragma unroll
        for (int i = 0; i < 4; ++i) {
            int4 vv = *reinterpret_cast<const int4*>(swad(QT, r, c0 + i * 16, 512));
            *reinterpret_cast<int4*>(dst + i * 16) = vv;
        }
    }
}

// ---- fused: per-wave ctx (head w) -> 1/sum scale -> rp GEMM -> MbT --------
__global__ __launch_bounds__(256) void ctx_rp(
    const ushort* __restrict__ kst3, const ushort* __restrict__ vst3,
    const ushort* __restrict__ kst4, const ushort* __restrict__ vst4,
    const float* __restrict__ partial, const ushort* __restrict__ RpT,
    ushort* __restrict__ MbT)
{
    __shared__ float rsv[256];
    __shared__ __align__(16) char ctile[4][64 * 128];   // per-head 64 x 128B swizzled
    int b = blockIdx.x, t = threadIdx.x;
    int w = t >> 6, l = t & 63, l15 = l & 15, rg = l >> 4;  // w = head g
    // reduce token-softmax partials -> 1/sum
    {
        float s = 0.f;
        for (int ch = 0; ch < 16; ++ch) s += partial[((size_t)b * 16 + ch) * 256 + t];
        rsv[t] = 1.f / s;
    }
    // ctx for head g = w : C[d][e] = sum_tok ks[d][tok]*vs[e][tok]
    const ushort* ks; const ushort* vs; int ntok;
    if (w < 2) { ntok = 256; ks = kst3 + (long)(b * 2 + w) * 64 * 256; vs = vst3 + (long)(b * 2 + w) * 64 * 256; }
    else       { ntok = 64;  ks = kst4 + (long)(b * 2 + (w - 2)) * 64 * 64; vs = vst4 + (long)(b * 2 + (w - 2)) * 64 * 64; }
    f32x4 acc[4][4];
#pragma unroll
    for (int m = 0; m < 4; ++m)
#pragma unroll
        for (int n = 0; n < 4; ++n) acc[m][n] = (f32x4){0.f, 0.f, 0.f, 0.f};
    for (int kc = 0; kc < (ntok >> 5); ++kc) {
        bf16x8 a[4];
#pragma unroll
        for (int mt = 0; mt < 4; ++mt)
            a[mt] = *reinterpret_cast<const bf16x8*>(&ks[(size_t)(mt * 16 + l15) * ntok + kc * 32 + rg * 8]);
#pragma unroll
        for (int nt = 0; nt < 4; ++nt) {
            bf16x8 bfr = *reinterpret_cast<const bf16x8*>(&vs[(size_t)(nt * 16 + l15) * ntok + kc * 32 + rg * 8]);
#pragma unroll
            for (int mt = 0; mt < 4; ++mt) acc[mt][nt] = MFMA(a[mt], bfr, acc[mt][nt]);
        }
    }
    __syncthreads();   // rsv ready
    // scale rows (d-axis) by 1/sum, write bf16 -> ctile (swizzled transpose)
#pragma unroll
    for (int mt = 0; mt < 4; ++mt)
#pragma unroll
        for (int j = 0; j < 4; ++j) {
            int row = mt * 16 + rg * 4 + j;
            float sc = rsv[w * 64 + row];
#pragma unroll
            for (int nt = 0; nt < 4; ++nt)
                *reinterpret_cast<ushort*>(swad(ctile[w], row, (nt * 16 + l15) * 2, 128))
                    = f2b(acc[mt][nt][j] * sc);
        }
    __syncthreads();
    // rp GEMM: Mb[n][g*64+d] = sum_e ctx'[d][e] * rp[g*64+e][n]
    bf16x8 a2[4][2];
#pragma unroll
    for (int m = 0; m < 4; ++m)
#pragma unroll
        for (int kc = 0; kc < 2; ++kc)
            a2[m][kc] = *reinterpret_cast<const bf16x8*>(
                swad(ctile[w], m * 16 + l15, (kc * 32 + rg * 8) * 2, 128));
#pragma unroll
    for (int nt = 0; nt < 8; ++nt) {
        f32x4 acc2[4];
#pragma unroll
        for (int m = 0; m < 4; ++m) acc2[m] = (f32x4){0.f, 0.f, 0.f, 0.f};
#pragma unroll
        for (int kc = 0; kc < 2; ++kc) {
            bf16x8 bfr = *reinterpret_cast<const bf16x8*>(
                &RpT[(size_t)(nt * 16 + l15) * 256 + w * 64 + kc * 32 + rg * 8]);
#pragma unroll
            for (int m = 0; m < 4; ++m) acc2[m] = MFMA(a2[m][kc], bfr, acc2[m]);
        }
        int n = nt * 16 + l15;
#pragma unroll
        for (int m = 0; m < 4; ++m) {
            unsigned int u0 = (unsigned int)f2b(acc2[m][0]) | ((unsigned int)f2b(acc2[m][1]) << 16);
            unsigned int u1 = (unsigned int)f2b(acc2[m][2]) | ((unsigned int)f2b(acc2[m][3]) << 16);
            uint2 uu; uu.x = u0; uu.y = u1;
            *reinterpret_cast<uint2*>(&MbT[((long)b * 128 + n) * 256 + w * 64 + m * 16 + rg * 4]) = uu;
        }
    }
}

// ---- fused (64 rows, 512 thr, 32KB LDS -> 4 blk/CU), dual-buffer phase B
//      + software-pipelined W fragments in the MLP
__global__ __launch_bounds__(512, 4) void attn_mlp(
    const ushort* __restrict__ qexp, const ushort* __restrict__ MbT,
    const float* __restrict__ rpb, const float* __restrict__ f2,
    const float* __restrict__ lnw, const float* __restrict__ lnb,
    const ushort* __restrict__ W1t, const float* __restrict__ ff1b,
    const ushort* __restrict__ W2t, const float* __restrict__ ff2b,
    float* __restrict__ out)
{
    __shared__ __align__(16) char smem[32768];
    char* XN = smem;            // qexp h1 stage -> xn (64 x 256B swizzled)
    char* R2 = smem + 16384;    // qexp h0 stage -> LN stats -> hid quarter (64 x 256B swz)
    float* Ps = reinterpret_cast<float*>(R2);                 // [64][8] row sums
    float* Pq = reinterpret_cast<float*>(R2 + 2048);          // [64][8] row sumsq
    float* MR = reinterpret_cast<float*>(R2 + 4096);          // [64] mean
    float* RR = reinterpret_cast<float*>(R2 + 4352);          // [64] rstd
    int t = threadIdx.x;
    long base = (long)blockIdx.x * 64;
    int b = blockIdx.x >> 4;
    int w = t >> 6, l = t & 63, l15 = l & 15, rg = l >> 4;
    int col = w * 16 + l15;

    // -------- prefetch: both qexp halves + f2 residual + Mb B-frags --------
    int sr = t >> 3, sc = (t & 7) * 32;
    const char* qsrc = (const char*)qexp + (base + sr) * 512 + sc;
    int4 q00 = *reinterpret_cast<const int4*>(qsrc);
    int4 q01 = *reinterpret_cast<const int4*>(qsrc + 16);
    int4 q10 = *reinterpret_cast<const int4*>(qsrc + 256);
    int4 q11 = *reinterpret_cast<const int4*>(qsrc + 256 + 16);
    float fpre[4][4];
#pragma unroll
    for (int m = 0; m < 4; ++m)
#pragma unroll
        for (int j = 0; j < 4; ++j)
            fpre[m][j] = f2[(base + m * 16 + rg * 4 + j) * 128 + col];
    const ushort* mb = MbT + (long)b * 128 * 256;
    bf16x8 mbfr[8];
#pragma unroll
    for (int kc2 = 0; kc2 < 8; ++kc2)
        mbfr[kc2] = *reinterpret_cast<const bf16x8*>(&mb[(size_t)col * 256 + kc2 * 32 + rg * 8]);

    // Phase B': stage BOTH halves (h0->R2, h1->XN), one barrier, 32 MFMAs
    *reinterpret_cast<int4*>(swad(R2, sr, sc, 256)) = q00;
    *reinterpret_cast<int4*>(swad(R2, sr, sc + 16, 256)) = q01;
    *reinterpret_cast<int4*>(swad(XN, sr, sc, 256)) = q10;
    *reinterpret_cast<int4*>(swad(XN, sr, sc + 16, 256)) = q11;
    __syncthreads();
    f32x4 accC[4];
#pragma unroll
    for (int m = 0; m < 4; ++m) accC[m] = (f32x4){0.f, 0.f, 0.f, 0.f};
#pragma unroll
    for (int kc2 = 0; kc2 < 8; ++kc2) {
        char* buf = (kc2 < 4) ? R2 : XN;
        int kc = kc2 & 3;
#pragma unroll
        for (int m = 0; m < 4; ++m) {
            bf16x8 a = *reinterpret_cast<const bf16x8*>(
                swad(buf, m * 16 + l15, (kc * 32 + rg * 8) * 2, 256));
            accC[m] = MFMA(a, mbfr[kc2], accC[m]);
        }
    }
    __syncthreads();   // all qexp reads done; R2/XN reusable

    // residual x = fpre + attn + rpb -> xres regs; LN partials via shfl -> Ps/Pq
    float xres[4][4];
    {
        float bias = rpb[col];
#pragma unroll
        for (int m = 0; m < 4; ++m)
#pragma unroll
            for (int j = 0; j < 4; ++j) {
                int row = m * 16 + rg * 4 + j;
                float xv = fpre[m][j] + accC[m][j] + bias;
                xres[m][j] = xv;
                float s = xv, q = xv * xv;
#pragma unroll
                for (int msk = 1; msk <= 8; msk <<= 1) {
                    s += __shfl_xor(s, msk, 64);
                    q += __shfl_xor(q, msk, 64);
                }
                if (l15 == 0) { Ps[row * 8 + w] = s; Pq[row * 8 + w] = q; }
            }
    }
    __syncthreads();
    if (t < 64) {
        float4 s0 = *reinterpret_cast<float4*>(&Ps[t * 8]);
        float4 s1 = *reinterpret_cast<float4*>(&Ps[t * 8 + 4]);
        float4 q0 = *reinterpret_cast<float4*>(&Pq[t * 8]);
        float4 q1 = *reinterpret_cast<float4*>(&Pq[t * 8 + 4]);
        float s = s0.x + s0.y + s0.z + s0.w + s1.x + s1.y + s1.z + s1.w;
        float q = q0.x + q0.y + q0.z + q0.w + q1.x + q1.y + q1.z + q1.w;
        float mean = s * (1.f / 128.f);
        float var = q * (1.f / 128.f) - mean * mean;
        MR[t] = mean;
        RR[t] = rsqrtf(var + EPSF);
    }
    __syncthreads();
    {
        float lw = lnw[col], lb = lnb[col];
#pragma unroll
        for (int m = 0; m < 4; ++m)
#pragma unroll
            for (int j = 0; j < 4; ++j) {
                int row = m * 16 + rg * 4 + j;
                float o = (xres[m][j] - MR[row]) * RR[row] * lw + lb;
                *reinterpret_cast<ushort*>(swad(XN, row, col * 2, 256)) = f2b(o);
            }
    }
    __syncthreads();   // MR/RR consumed; R2 free for hid

    // MLP K-quartered with software-pipelined W fragments:
    //   preload W1(0); in E(q) prefetch W2(q); in F(q) prefetch W1(q+1)
    f32x4 accF[4];
#pragma unroll
    for (int m = 0; m < 4; ++m) accF[m] = (f32x4){0.f, 0.f, 0.f, 0.f};
    bf16x8 w1f[4], w2f[4];
#pragma unroll
    for (int kc = 0; kc < 4; ++kc)
        w1f[kc] = *reinterpret_cast<const bf16x8*>(&W1t[(size_t)col * 128 + kc * 32 + rg * 8]);
#pragma unroll
    for (int q = 0; q < 4; ++q) {
        // prefetch W2 frags for F(q) (consumed after next barrier)
#pragma unroll
        for (int kc = 0; kc < 4; ++kc)
            w2f[kc] = *reinterpret_cast<const bf16x8*>(
                &W2t[(size_t)col * 512 + q * 128 + kc * 32 + rg * 8]);
        // E(q): xn @ W1(q) + gelu -> R2
        {
            f32x4 acc[4];
#pragma unroll
            for (int m = 0; m < 4; ++m) acc[m] = (f32x4){0.f, 0.f, 0.f, 0.f};
#pragma unroll
            for (int kc = 0; kc < 4; ++kc)
#pragma unroll
                for (int m = 0; m < 4; ++m) {
                    bf16x8 a = *reinterpret_cast<const bf16x8*>(
                        swad(XN, m * 16 + l15, (kc * 32 + rg * 8) * 2, 256));
                    acc[m] = MFMA(a, w1f[kc], acc[m]);
                }
            float b1 = ff1b[q * 128 + col];
#pragma unroll
            for (int m = 0; m < 4; ++m)
#pragma unroll
                for (int j = 0; j < 4; ++j)
                    *reinterpret_cast<ushort*>(swad(R2, m * 16 + rg * 4 + j, col * 2, 256))
                        = f2b(gelu_f(acc[m][j] + b1));
        }
        __syncthreads();
        // prefetch W1 frags for E(q+1)
        if (q < 3) {
#pragma unroll
            for (int kc = 0; kc < 4; ++kc)
                w1f[kc] = *reinterpret_cast<const bf16x8*>(
                    &W1t[(size_t)((q + 1) * 128 + col) * 128 + kc * 32 + rg * 8]);
        }
        // F(q): hid @ W2(q) accumulate
#pragma unroll
        for (int kc = 0; kc < 4; ++kc)
#pragma unroll
            for (int m = 0; m < 4; ++m) {
                bf16x8 a = *reinterpret_cast<const bf16x8*>(
                    swad(R2, m * 16 + l15, (kc * 32 + rg * 8) * 2, 256));
                accF[m] = MFMA(a, w2f[kc], accF[m]);
            }
        if (q < 3) __syncthreads();
    }
    // epilogue: out = x + mlp + b2
    {
        float b2 = ff2b[col];
#pragma unroll
        for (int m = 0; m < 4; ++m)
#pragma unroll
            for (int j = 0; j < 4; ++j) {
                int row = m * 16 + rg * 4 + j;
                long g = (base + row) * 128 + col;
                out[g] = xres[m][j] + accF[m][j] + b2;
            }
    }
}

extern "C" void kernel_launch(void* const* d_in, const int* in_sizes, int n_in,
                              void* d_out, int out_size, void* d_ws, size_t ws_size,
                              hipStream_t stream) {
    const float* f2   = (const float*)d_in[0];
    const float* f3   = (const float*)d_in[1];
    const float* f4   = (const float*)d_in[2];
    const float* pe2  = (const float*)d_in[3];
    const float* pe3  = (const float*)d_in[4];
    const float* pe4  = (const float*)d_in[5];
    const float* ln1w = (const float*)d_in[6];
    const float* ln1b = (const float*)d_in[7];
    const float* ln2w = (const float*)d_in[8];
    const float* ln2b = (const float*)d_in[9];
    const float* ln3w = (const float*)d_in[10];
    const float* ln3b = (const float*)d_in[11];
    const float* ln4w = (const float*)d_in[12];
    const float* ln4b = (const float*)d_in[13];
    const float* q1w  = (const float*)d_in[14];
    const float* q1b  = (const float*)d_in[15];
    const float* k1w  = (const float*)d_in[16];
    const float* k1b  = (const float*)d_in[17];
    const float* v1w  = (const float*)d_in[18];
    const float* v1b  = (const float*)d_in[19];
    const float* q2w  = (const float*)d_in[20];
    const float* q2b  = (const float*)d_in[21];
    const float* k2w  = (const float*)d_in[22];
    const float* k2b  = (const float*)d_in[23];
    const float* v2w  = (const float*)d_in[24];
    const float* v2b  = (const float*)d_in[25];
    const float* rpw  = (const float*)d_in[26];
    const float* rpb  = (const float*)d_in[27];
    const float* ff1w = (const float*)d_in[28];
    const float* ff1b = (const float*)d_in[29];
    const float* ff2w = (const float*)d_in[30];
    const float* ff2b = (const float*)d_in[31];

    char* ws = (char*)d_ws;
    size_t off = 0;
    ushort* qexp  = (ushort*)(ws + off); off += (size_t)BB * NN2 * 256 * 2;
    ushort* kst3  = (ushort*)(ws + off); off += (size_t)BB * 2 * 64 * NN3 * 2;
    ushort* vst3  = (ushort*)(ws + off); off += (size_t)BB * 2 * 64 * NN3 * 2;
    ushort* kst4  = (ushort*)(ws + off); off += (size_t)BB * 2 * 64 * NN4 * 2;
    ushort* vst4  = (ushort*)(ws + off); off += (size_t)BB * 2 * 64 * NN4 * 2;
    ushort* MbT   = (ushort*)(ws + off); off += (size_t)BB * 128 * 256 * 2;
    ushort* Wqt   = (ushort*)(ws + off); off += 256 * 128 * 2;
    ushort* Wkv3t = (ushort*)(ws + off); off += 256 * 128 * 2;
    ushort* Wkv4t = (ushort*)(ws + off); off += 256 * 128 * 2;
    ushort* W1t   = (ushort*)(ws + off); off += 512 * 128 * 2;
    ushort* W2t   = (ushort*)(ws + off); off += 128 * 512 * 2;
    ushort* RpT   = (ushort*)(ws + off); off += 128 * 256 * 2;
    float*  peq   = (float*)(ws + off);  off += (size_t)NN2 * 256 * 4;
    float*  pekv3 = (float*)(ws + off);  off += (size_t)NN3 * 256 * 4;
    float*  pekv4 = (float*)(ws + off);  off += (size_t)NN4 * 256 * 4;
    float*  partial = (float*)(ws + off); off += (size_t)BB * 16 * 256 * 4;

    prep_all<<<16 + 1344, 256, 0, stream>>>(q1w, q2w, k1w, v1w, k2w, v2w, ff1w, ff2w, rpw,
                                            pe2, pe3, pe4, q1b, q2b, k1b, v1b, k2b, v2b,
                                            Wqt, Wkv3t, Wkv4t, W1t, W2t, RpT,
                                            peq, pekv3, pekv4);
    kv_both<<<1280, 256, 0, stream>>>(f3, f4, ln2w, ln2b, ln3w, ln3b, Wkv3t, Wkv4t,
                                      pekv3, pekv4, kst3, vst3, kst4, vst4);
    q_mfma<<<BB * NN2 / 64, 512, 0, stream>>>(f2, ln1w, ln1b, Wqt, peq, qexp, partial);
    ctx_rp<<<BB, 256, 0, stream>>>(kst3, vst3, kst4, vst4, partial, RpT, MbT);
    attn_mlp<<<BB * NN2 / 64, 512, 0, stream>>>(qexp, MbT, rpb, f2,
                                                ln4w, ln4b, W1t, ff1b, W2t, ff2b, (float*)d_out);
}